// Round 12
// baseline (151.407 us; speedup 1.0000x reference)
//
#include <hip/hip_runtime.h>
#include <hip/hip_bf16.h>

#define D_MODEL 1024
#define NHEAD 16
#define DH 64
#define BSZ 2
#define SEQ 2048
#define MROWS (BSZ*SEQ)
#define SCL_Q 0.1803368801111204f   /* (1/sqrt(64)) * log2(e) */
#define CHSZ2 33792                 /* partial chunk: 256*64 bf16 O + 256 f32 l */

typedef __attribute__((ext_vector_type(4))) float f32x4;
typedef __attribute__((ext_vector_type(8))) __bf16 bf16x8;
typedef __attribute__((ext_vector_type(8))) unsigned short u16x8;

__device__ __forceinline__ float b2f(unsigned short u) {
    union { unsigned int i; float f; } v; v.i = ((unsigned int)u) << 16; return v.f;
}
__device__ __forceinline__ unsigned short f2b(float f) {
    union { float f; unsigned int i; } v; v.f = f;
    unsigned int u = v.i;
    u += 0x7fffu + ((u >> 16) & 1u);
    return (unsigned short)(u >> 16);
}

// Partial slots live in ws regions that are DEAD during attn/merge:
//   [8MB,14MB)  = Wq/Wk/Wv bf16 (dead after gemm_qkv)   -> slots 0..185
//   [32MB,40MB) = Vb (dead after vtrans)                -> slots 186..433
//   [48.25MB..) = old partial area (proven safe)        -> slots 434..575
__device__ __forceinline__ char* slotptr(char* wsb, int s) {
    const size_t MB = 1024*1024;
    if (s < 186)  return wsb + 8*MB            + (size_t)s * CHSZ2;
    if (s < 434)  return wsb + 32*MB           + (size_t)(s - 186) * CHSZ2;
    return              wsb + 48*MB + 262144   + (size_t)(s - 434) * CHSZ2;
}

#define GLDS16(gptr, lptr) \
    __builtin_amdgcn_global_load_lds((__attribute__((address_space(1))) void*)(gptr), \
                                     (__attribute__((address_space(3))) void*)(lptr), 16, 0, 0)

// ---------------- f32 -> bf16 convert: x + 4 weight matrices in one launch ----------------
__global__ __launch_bounds__(256) void cvt5(
    const float* __restrict__ sx,
    const float* __restrict__ s1, const float* __restrict__ s2,
    const float* __restrict__ s3, const float* __restrict__ s4,
    unsigned short* __restrict__ dx,
    unsigned short* __restrict__ d1, unsigned short* __restrict__ d2,
    unsigned short* __restrict__ d3, unsigned short* __restrict__ d4)
{
    const int seg = blockIdx.y;
    const float* src; unsigned short* dst; int n4;
    if (seg == 0)      { src = sx; dst = dx; n4 = MROWS*D_MODEL/4; }
    else if (seg == 1) { src = s1; dst = d1; n4 = D_MODEL*D_MODEL/4; }
    else if (seg == 2) { src = s2; dst = d2; n4 = D_MODEL*D_MODEL/4; }
    else if (seg == 3) { src = s3; dst = d3; n4 = D_MODEL*D_MODEL/4; }
    else               { src = s4; dst = d4; n4 = D_MODEL*D_MODEL/4; }
    int i = blockIdx.x * 256 + threadIdx.x;
    int stride = gridDim.x * 256;
    for (; i < n4; i += stride) {
        float4 v = ((const float4*)src)[i];
        ushort4 o;
        o.x = f2b(v.x); o.y = f2b(v.y); o.z = f2b(v.z); o.w = f2b(v.w);
        ((ushort4*)dst)[i] = o;
    }
}

// ---------------- QKV GEMM: out = x @ W^T + b, head-split bf16 output, dbuf ----------------
// Q output (z==0) is pre-scaled by SCL_Q so attention needs no per-score scaling.
__global__ __launch_bounds__(256) void gemm_qkv(
    const unsigned short* __restrict__ X,
    const unsigned short* __restrict__ Wq, const unsigned short* __restrict__ Wk,
    const unsigned short* __restrict__ Wv,
    const float* __restrict__ bq, const float* __restrict__ bk, const float* __restrict__ bv,
    unsigned short* __restrict__ Qo, unsigned short* __restrict__ Ko, unsigned short* __restrict__ Vo)
{
    __shared__ unsigned short lsA[2][128*32];
    __shared__ unsigned short lsB[2][128*32];
    const int tid = threadIdx.x;
    const int z = blockIdx.z;
    const unsigned short* W = (z==0) ? Wq : (z==1) ? Wk : Wv;
    const float* bias = (z==0) ? bq : (z==1) ? bk : bv;
    unsigned short* Out = (z==0) ? Qo : (z==1) ? Ko : Vo;
    const int tM = blockIdx.y * 128;
    const int tN = blockIdx.x * 128;
    const int w = tid >> 6, lane = tid & 63;
    const int wr = w >> 1, wc = w & 1;
    const int lr = lane & 15, lk = lane >> 4;
    const f32x4 fz = {0.f, 0.f, 0.f, 0.f};
    f32x4 acc[4][4];
    #pragma unroll
    for (int m = 0; m < 4; m++)
        #pragma unroll
        for (int n = 0; n < 4; n++) acc[m][n] = fz;

    const int e0 = tid, e1 = 256 + tid;
    const int r0 = e0 >> 2, c0 = ((e0 & 3) ^ (r0 & 3)) * 8;
    const int r1 = e1 >> 2, c1 = ((e1 & 3) ^ (r1 & 3)) * 8;

#define GEMM_STAGE(buf, k0_) do { \
        GLDS16(X + (size_t)(tM + r0) * D_MODEL + (k0_) + c0, &lsA[buf][e0 * 8]); \
        GLDS16(X + (size_t)(tM + r1) * D_MODEL + (k0_) + c1, &lsA[buf][e1 * 8]); \
        GLDS16(W + (size_t)(tN + r0) * D_MODEL + (k0_) + c0, &lsB[buf][e0 * 8]); \
        GLDS16(W + (size_t)(tN + r1) * D_MODEL + (k0_) + c1, &lsB[buf][e1 * 8]); \
    } while (0)

    GEMM_STAGE(0, 0);
    __syncthreads();
    int cur = 0;
    for (int k0 = 0; k0 < D_MODEL; k0 += 32) {
        if (k0 + 32 < D_MODEL) GEMM_STAGE(cur ^ 1, k0 + 32);
        bf16x8 af[4], bfr[4];
        #pragma unroll
        for (int m = 0; m < 4; m++) {
            int row = wr*64 + m*16 + lr;
            af[m] = *(const bf16x8*)&lsA[cur][row*32 + ((lk ^ (row & 3)) * 8)];
        }
        #pragma unroll
        for (int n = 0; n < 4; n++) {
            int row = wc*64 + n*16 + lr;
            bfr[n] = *(const bf16x8*)&lsB[cur][row*32 + ((lk ^ (row & 3)) * 8)];
        }
        #pragma unroll
        for (int m = 0; m < 4; m++)
            #pragma unroll
            for (int n = 0; n < 4; n++)
                acc[m][n] = __builtin_amdgcn_mfma_f32_16x16x32_bf16(af[m], bfr[n], acc[m][n], 0, 0, 0);
        __syncthreads();
        cur ^= 1;
    }
#undef GEMM_STAGE
    const float qscl = (z == 0) ? SCL_Q : 1.0f;
    #pragma unroll
    for (int m = 0; m < 4; m++) {
        int ibase = tM + wr*64 + m*16 + lk*4;
        #pragma unroll
        for (int n = 0; n < 4; n++) {
            int j = tN + wc*64 + n*16 + lr;
            float bj = bias[j];
            int h = j >> 6, d = j & 63;
            #pragma unroll
            for (int r = 0; r < 4; r++) {
                int row = ibase + r;
                int b = row >> 11, s = row & 2047;
                Out[((size_t)(b*NHEAD + h) * SEQ + s) * DH + d] = f2b((acc[m][n][r] + bj) * qscl);
            }
        }
    }
}

// ---------------- Output GEMM: out = A @ W^T + b, f32 output, 128x64 tile, 8 waves ----------------
__global__ __launch_bounds__(512) void gemm_out(
    const unsigned short* __restrict__ X, const unsigned short* __restrict__ W,
    const float* __restrict__ bias, float* __restrict__ Out)
{
    __shared__ unsigned short lsA[2][128*32];
    __shared__ unsigned short lsB[2][64*32];
    const int tid = threadIdx.x;
    const int tM = blockIdx.y * 128;
    const int tN = blockIdx.x * 64;
    const int w = tid >> 6, lane = tid & 63;
    const int wr = w >> 1, wc = w & 1;
    const int lr = lane & 15, lk = lane >> 4;
    const f32x4 fz = {0.f, 0.f, 0.f, 0.f};
    f32x4 acc[2][2];
    #pragma unroll
    for (int m = 0; m < 2; m++)
        #pragma unroll
        for (int n = 0; n < 2; n++) acc[m][n] = fz;

    const int ra = tid >> 2, ca = ((tid & 3) ^ (ra & 3)) * 8;
    const int eb = tid & 255;
    const int rb = eb >> 2, cb = ((eb & 3) ^ (rb & 3)) * 8;

#define OUT_STAGE(buf, k0_) do { \
        GLDS16(X + (size_t)(tM + ra) * D_MODEL + (k0_) + ca, &lsA[buf][tid * 8]); \
        if (tid < 256) GLDS16(W + (size_t)(tN + rb) * D_MODEL + (k0_) + cb, &lsB[buf][eb * 8]); \
    } while (0)

    OUT_STAGE(0, 0);
    __syncthreads();
    int cur = 0;
    for (int k0 = 0; k0 < D_MODEL; k0 += 32) {
        if (k0 + 32 < D_MODEL) OUT_STAGE(cur ^ 1, k0 + 32);
        bf16x8 af[2], bfr[2];
        #pragma unroll
        for (int m = 0; m < 2; m++) {
            int row = wr*32 + m*16 + lr;
            af[m] = *(const bf16x8*)&lsA[cur][row*32 + ((lk ^ (row & 3)) * 8)];
        }
        #pragma unroll
        for (int n = 0; n < 2; n++) {
            int row = wc*32 + n*16 + lr;
            bfr[n] = *(const bf16x8*)&lsB[cur][row*32 + ((lk ^ (row & 3)) * 8)];
        }
        #pragma unroll
        for (int m = 0; m < 2; m++)
            #pragma unroll
            for (int n = 0; n < 2; n++)
                acc[m][n] = __builtin_amdgcn_mfma_f32_16x16x32_bf16(af[m], bfr[n], acc[m][n], 0, 0, 0);
        __syncthreads();
        cur ^= 1;
    }
#undef OUT_STAGE
    #pragma unroll
    for (int m = 0; m < 2; m++) {
        int ibase = tM + wr*32 + m*16 + lk*4;
        #pragma unroll
        for (int n = 0; n < 2; n++) {
            int j = tN + wc*32 + n*16 + lr;
            float bj = bias[j];
            #pragma unroll
            for (int r = 0; r < 4; r++)
                Out[(size_t)(ibase + r) * D_MODEL + j] = acc[m][n][r] + bj;
        }
    }
}

// ---------------- V transpose: [bh][s][d] -> [bh][d][s] ----------------
__global__ __launch_bounds__(256) void vtrans(const unsigned short* __restrict__ V,
                                              unsigned short* __restrict__ Vt) {
    __shared__ unsigned short t[64][80];
    const int bh = blockIdx.y;
    const int s0 = blockIdx.x * 64;
    const int tid = threadIdx.x;
    #pragma unroll
    for (int i = 0; i < 2; i++) {
        int e = i*256 + tid;
        int r = e >> 3, c = e & 7;
        u16x8 v = *(const u16x8*)&V[((size_t)bh * SEQ + s0 + r) * DH + c*8];
        *(u16x8*)&t[r][c*8] = v;
    }
    __syncthreads();
    #pragma unroll
    for (int i = 0; i < 2; i++) {
        int e = i*256 + tid;
        int d = e >> 3, c = e & 7;
        u16x8 o;
        #pragma unroll
        for (int j = 0; j < 8; j++) o[j] = t[c*8 + j][d];
        *(u16x8*)&Vt[((size_t)bh * DH + d) * SEQ + s0 + c*8] = o;
    }
}

// ---------------- qer[b,h,l] = dot(Qscaled[b,h,l,:], Er[l,:])  (inherits SCL_Q) ----------
// Only l >= 1024 is ever consumed (odd-k relative bias) -> compute only that half.
__global__ __launch_bounds__(256) void qer_k(const unsigned short* __restrict__ Q,
                                             const float* __restrict__ Er,
                                             float* __restrict__ qer) {
    int gw = blockIdx.x * 4 + (threadIdx.x >> 6);   // 0 .. 32*1024-1
    int lane = threadIdx.x & 63;
    int bh = gw >> 10;
    int l = 1024 + (gw & 1023);
    float p = b2f(Q[((size_t)bh * SEQ + l) * DH + lane]) * Er[l * DH + lane];
    #pragma unroll
    for (int m = 32; m >= 1; m >>= 1) p += __shfl_xor(p, m, 64);
    if (lane == 0) qer[(size_t)bh * SEQ + l] = p;
}

// ---------------- flash attention, swapped-QK, QBLK=256, 8 waves x 32q, chunked ------------
// Empirical: only 2 blocks/CU ever co-reside (occupancy pinned ~23-25% for every 4-wave
// variant r7-r11). So maximize waves per block: 512 thr = 8 waves x 32q (keeps r7's
// K/V-read amortization), LDS = 64KB (2 blocks = 128KB <= 160KB) -> 16 waves/CU.
// Fixed-shift softmax (m == 0): partials are directly summable. Chunks <= 8 k-tiles,
// 20/bh, grid 640, work-descending; j<=1 single-pass, j>=2 writes partial slots.
__global__ __launch_bounds__(512, 4) void attn_k(
    const unsigned short* __restrict__ Q, const unsigned short* __restrict__ Kg,
    const unsigned short* __restrict__ Vt, const float* __restrict__ qer,
    unsigned short* __restrict__ Om, char* __restrict__ wsb)
{
    __shared__ unsigned short lsK[2][64*64];   // 16 KB
    __shared__ unsigned short lsV[2][64*64];   // 16 KB
    __shared__ unsigned short lsP[256*64];     // 32 KB
    // chunk tables (20/bh): j (q-tile of 256 rows), kt0, ktN, slot (255 = single)
    const unsigned char jt[20]  = {7,7,7,7, 5,5,5, 3,3, 1, 6,6,6,6, 4,4, 4, 2,2, 0};
    const unsigned char k0t[20] = {0,8,16,24, 0,8,16, 0,8, 0, 0,7,14,21, 0,7, 14, 0,6, 0};
    const unsigned char k1t[20] = {8,16,24,32, 8,16,24, 8,16, 8, 7,14,21,28, 7,14, 20, 6,12, 4};
    const unsigned char st20[20]= {14,15,16,17, 7,8,9, 2,3, 255, 10,11,12,13, 4,5, 6, 0,1, 255};
    const int id = blockIdx.x;
    const int bh = id & 31;
    const int u = id >> 5;
    const int j = jt[u];
    const int kt0 = k0t[u];
    const int ktN = k1t[u];
    const int sl = st20[u];
    const int b = bh >> 4, h = bh & 15;
    const int tid = threadIdx.x;
    const int w = tid >> 6, lane = tid & 63;
    const int lr = lane & 15, lk = lane >> 4;
    const int q0 = w*32 + lr, q1 = q0 + 16;     // 0..255
    const int qrow0 = j*256 + q0, qrow1 = qrow0 + 16;
    const f32x4 fz = {0.f, 0.f, 0.f, 0.f};

    const unsigned short* Qr0 = Q + ((size_t)bh * SEQ + qrow0) * DH;
    const unsigned short* Qr1 = Q + ((size_t)bh * SEQ + qrow1) * DH;
    bf16x8 bqa0 = *(const bf16x8*)&Qr0[lk*8];
    bf16x8 bqa1 = *(const bf16x8*)&Qr0[32 + lk*8];
    bf16x8 bqb0 = *(const bf16x8*)&Qr1[lk*8];
    bf16x8 bqb1 = *(const bf16x8*)&Qr1[32 + lk*8];

    // staging: one 16B load per thread per matrix per 64x64 tile (pre-swizzled source)
    const int sr = tid >> 3, sc = ((tid & 7) ^ (sr & 7)) * 8;
    const unsigned short* kst = Kg + ((size_t)bh * SEQ + kt0*64 + sr) * DH + sc;
    const unsigned short* vst = Vt + ((size_t)bh * DH + sr) * SEQ + kt0*64 + sc;
    const float* qb = qer + (size_t)bh * SEQ + 1024 + kt0*32 + lk*2;

#define ATTN_STAGE(buf) do { \
        GLDS16(kst, &lsK[buf][tid * 8]); kst += 64*DH; \
        GLDS16(vst, &lsV[buf][tid * 8]); vst += 64; \
    } while (0)

    f32x4 o0[4], o1[4];
    #pragma unroll
    for (int df = 0; df < 4; df++) { o0[df] = fz; o1[df] = fz; }
    float lp0 = 0.0f, lp1 = 0.0f;   // per-lane row-sum partials (this lane's k slots)

    ATTN_STAGE(0);
    __syncthreads();
    int cur = 0;

    for (int kt = kt0; kt < ktN; kt++) {
        float2 bv[4];
        #pragma unroll
        for (int kf = 0; kf < 4; kf++) bv[kf] = *(const float2*)(qb + kf*8);
        qb += 32;
        if (kt + 1 < ktN) ATTN_STAGE(cur ^ 1);   // prefetch; drains at end-of-iter barrier
        // QK^T (swapped): st/su[kf][r] = S[k = kt*64+kf*16+lk*4+r][qrow0/qrow1], log2 domain
        float st[4][4], su[4][4];
        __builtin_amdgcn_s_setprio(1);
        #pragma unroll
        for (int kf = 0; kf < 4; kf++) {
            int row = kf*16 + lr;
            bf16x8 a0 = *(const bf16x8*)&lsK[cur][row*64 + ((lk ^ (row & 7)) * 8)];
            bf16x8 a1 = *(const bf16x8*)&lsK[cur][row*64 + (((4 + lk) ^ (row & 7)) * 8)];
            f32x4 zv = fz, yv = fz;
            zv = __builtin_amdgcn_mfma_f32_16x16x32_bf16(a0, bqa0, zv, 0, 0, 0);
            zv = __builtin_amdgcn_mfma_f32_16x16x32_bf16(a1, bqa1, zv, 0, 0, 0);
            yv = __builtin_amdgcn_mfma_f32_16x16x32_bf16(a0, bqb0, yv, 0, 0, 0);
            yv = __builtin_amdgcn_mfma_f32_16x16x32_bf16(a1, bqb1, yv, 0, 0, 0);
            st[kf][0] = zv[0];
            st[kf][1] = zv[1] + bv[kf].x;
            st[kf][2] = zv[2];
            st[kf][3] = zv[3] + bv[kf].y;
            su[kf][0] = yv[0];
            su[kf][1] = yv[1] + bv[kf].x;
            su[kf][2] = yv[2];
            su[kf][3] = yv[3] + bv[kf].y;
        }
        __builtin_amdgcn_s_setprio(0);
        if (kt >= 4*j) {  // tiles that can cross the diagonal
            #pragma unroll
            for (int kf = 0; kf < 4; kf++) {
                int kg0 = kt*64 + kf*16 + lk*4;
                #pragma unroll
                for (int r = 0; r < 4; r++) {
                    if (kg0 + r > qrow0) st[kf][r] = -3.0e38f;
                    if (kg0 + r > qrow1) su[kf][r] = -3.0e38f;
                }
            }
        }
        // p = exp2(S) (fixed shift), per-lane partial row-sums, pack to LDS
        #pragma unroll
        for (int kf = 0; kf < 4; kf++) {
            float p0 = exp2f(st[kf][0]);
            float p1 = exp2f(st[kf][1]);
            float p2 = exp2f(st[kf][2]);
            float p3 = exp2f(st[kf][3]);
            lp0 += (p0 + p1) + (p2 + p3);
            union { __hip_bfloat162 h2[2]; unsigned long long u; } pk;
            pk.h2[0] = __float22bfloat162_rn(float2{p0, p1});
            pk.h2[1] = __float22bfloat162_rn(float2{p2, p3});
            *(unsigned long long*)&lsP[q0*64 + ((((kf<<2)|lk) ^ ((lr&7)<<1))<<2)] = pk.u;
            float s0 = exp2f(su[kf][0]);
            float s1 = exp2f(su[kf][1]);
            float s2 = exp2f(su[kf][2]);
            float s3 = exp2f(su[kf][3]);
            lp1 += (s0 + s1) + (s2 + s3);
            pk.h2[0] = __float22bfloat162_rn(float2{s0, s1});
            pk.h2[1] = __float22bfloat162_rn(float2{s2, s3});
            *(unsigned long long*)&lsP[q1*64 + ((((kf<<2)|lk) ^ ((lr&7)<<1))<<2)] = pk.u;
        }
        // P^T reads (own rows only -> same-wave lgkm dependency)
        bf16x8 pa0 = *(const bf16x8*)&lsP[q0*64 + ((lk ^ (lr&7))<<3)];
        bf16x8 pa1 = *(const bf16x8*)&lsP[q0*64 + (((4+lk) ^ (lr&7))<<3)];
        bf16x8 pb0 = *(const bf16x8*)&lsP[q1*64 + ((lk ^ (lr&7))<<3)];
        bf16x8 pb1 = *(const bf16x8*)&lsP[q1*64 + (((4+lk) ^ (lr&7))<<3)];
        // PV (swapped): shared V fragments feed both q-halves
        __builtin_amdgcn_s_setprio(1);
        #pragma unroll
        for (int df = 0; df < 4; df++) {
            int row = df*16 + lr;
            bf16x8 v0 = *(const bf16x8*)&lsV[cur][row*64 + ((lk ^ (row & 7)) * 8)];
            bf16x8 v1 = *(const bf16x8*)&lsV[cur][row*64 + (((4 + lk) ^ (row & 7)) * 8)];
            o0[df] = __builtin_amdgcn_mfma_f32_16x16x32_bf16(v0, pa0, o0[df], 0, 0, 0);
            o0[df] = __builtin_amdgcn_mfma_f32_16x16x32_bf16(v1, pa1, o0[df], 0, 0, 0);
            o1[df] = __builtin_amdgcn_mfma_f32_16x16x32_bf16(v0, pb0, o1[df], 0, 0, 0);
            o1[df] = __builtin_amdgcn_mfma_f32_16x16x32_bf16(v1, pb1, o1[df], 0, 0, 0);
        }
        __builtin_amdgcn_s_setprio(0);
        __syncthreads();
        cur ^= 1;
    }
#undef ATTN_STAGE
    // final row-sum reduction across the 4 lk groups (2 shuffles, once per chunk)
    float l0 = lp0 + __shfl_xor(lp0, 16, 64);
    l0 += __shfl_xor(l0, 32, 64);
    float l1 = lp1 + __shfl_xor(lp1, 16, 64);
    l1 += __shfl_xor(l1, 32, 64);
    if (sl != 255) {
        char* cb = slotptr(wsb, bh*18 + sl);
        unsigned short* ob = (unsigned short*)cb;
        #pragma unroll
        for (int df = 0; df < 4; df++) {
            ushort4 ov;
            ov.x = f2b(o0[df][0]); ov.y = f2b(o0[df][1]);
            ov.z = f2b(o0[df][2]); ov.w = f2b(o0[df][3]);
            *(ushort4*)&ob[q0*64 + df*16 + lk*4] = ov;
            ov.x = f2b(o1[df][0]); ov.y = f2b(o1[df][1]);
            ov.z = f2b(o1[df][2]); ov.w = f2b(o1[df][3]);
            *(ushort4*)&ob[q1*64 + df*16 + lk*4] = ov;
        }
        float* lv = (float*)(cb + 32768);
        if (lk == 0) { lv[q0] = l0; lv[q1] = l1; }
    } else {
        float inv0 = 1.0f / l0, inv1 = 1.0f / l1;
        #pragma unroll
        for (int df = 0; df < 4; df++) {
            ushort4 ov;
            ov.x = f2b(o0[df][0] * inv0);
            ov.y = f2b(o0[df][1] * inv0);
            ov.z = f2b(o0[df][2] * inv0);
            ov.w = f2b(o0[df][3] * inv0);
            *(ushort4*)&Om[((size_t)(b * SEQ + qrow0)) * D_MODEL + h*64 + df*16 + lk*4] = ov;
            ov.x = f2b(o1[df][0] * inv1);
            ov.y = f2b(o1[df][1] * inv1);
            ov.z = f2b(o1[df][2] * inv1);
            ov.w = f2b(o1[df][3] * inv1);
            *(ushort4*)&Om[((size_t)(b * SEQ + qrow1)) * D_MODEL + h*64 + df*16 + lk*4] = ov;
        }
    }
}

// ---------------- merge the 2-4 summable partials for each j >= 2 ----------------
__global__ __launch_bounds__(512) void attn_merge(char* __restrict__ wsb,
                                                  unsigned short* __restrict__ Om)
{
    const unsigned char offt[6] = {0,2,4,7,10,14};
    const unsigned char nct[6]  = {2,2,3,3,4,4};
    const int bh = blockIdx.x & 31, jj = blockIdx.x >> 5;   // jj 0..5 -> j = 2+jj
    const int b = bh >> 4, h = bh & 15, j = 2 + jj;
    const int nc = nct[jj];
    const int base = bh*18 + offt[jj];
    const int t = threadIdx.x;
    const int q = t >> 1, dh = (t & 1) * 32;
    float acc[32];
    #pragma unroll
    for (int i = 0; i < 32; i++) acc[i] = 0.f;
    float lsum = 0.f;
    for (int c = 0; c < nc; c++) {
        const char* cb = slotptr(wsb, base + c);
        const unsigned short* ob = (const unsigned short*)cb;
        const float* lv = (const float*)(cb + 32768);
        lsum += lv[q];
        #pragma unroll
        for (int i = 0; i < 4; i++) {
            u16x8 a = *(const u16x8*)&ob[q*64 + dh + i*8];
            #pragma unroll
            for (int r = 0; r < 8; r++) acc[i*8 + r] += b2f(a[r]);
        }
    }
    float inv = 1.0f / lsum;
    unsigned short* dst = Om + ((size_t)(b*SEQ + j*256 + q)) * D_MODEL + h*64 + dh;
    #pragma unroll
    for (int i = 0; i < 4; i++) {
        u16x8 ov;
        #pragma unroll
        for (int r = 0; r < 8; r++) ov[r] = f2b(acc[i*8 + r] * inv);
        *(u16x8*)&dst[i*8] = ov;
    }
}

extern "C" void kernel_launch(void* const* d_in, const int* in_sizes, int n_in,
                              void* d_out, int out_size, void* d_ws, size_t ws_size,
                              hipStream_t stream) {
    const float* x  = (const float*)d_in[0];
    const float* Wq = (const float*)d_in[1];
    const float* bq = (const float*)d_in[2];
    const float* Wk = (const float*)d_in[3];
    const float* bk = (const float*)d_in[4];
    const float* Wv = (const float*)d_in[5];
    const float* bv = (const float*)d_in[6];
    const float* Wo = (const float*)d_in[7];
    const float* bo = (const float*)d_in[8];
    const float* Er = (const float*)d_in[9];

    char* ws = (char*)d_ws;
    const size_t MB = 1024*1024;
    unsigned short* xb  = (unsigned short*)(ws);              // 8 MB: x bf16; reused as attn out
    unsigned short* Wqb = (unsigned short*)(ws + 8*MB);       // 2 MB each; region reused for partials
    unsigned short* Wkb = (unsigned short*)(ws + 10*MB);
    unsigned short* Wvb = (unsigned short*)(ws + 12*MB);
    unsigned short* Wob = (unsigned short*)(ws + 14*MB);
    unsigned short* Qb  = (unsigned short*)(ws + 16*MB);      // 8 MB
    unsigned short* Kb  = (unsigned short*)(ws + 24*MB);      // 8 MB
    unsigned short* Vb  = (unsigned short*)(ws + 32*MB);      // 8 MB ([bh][s][d]); reused for partials
    unsigned short* Vtb = (unsigned short*)(ws + 40*MB);      // 8 MB ([bh][d][s])
    float* qer          = (float*)(ws + 48*MB);               // 256 KB; partials tail after

    cvt5<<<dim3(1024, 5), 256, 0, stream>>>(x, Wq, Wk, Wv, Wo, xb, Wqb, Wkb, Wvb, Wob);

    gemm_qkv<<<dim3(8, 32, 3), 256, 0, stream>>>(xb, Wqb, Wkb, Wvb, bq, bk, bv, Qb, Kb, Vb);
    vtrans<<<dim3(32, 32), 256, 0, stream>>>(Vb, Vtb);
    qer_k<<<8192, 256, 0, stream>>>(Qb, Er, qer);
    attn_k<<<640, 512, 0, stream>>>(Qb, Kb, Vtb, qer, xb, ws);
    attn_merge<<<192, 512, 0, stream>>>(ws, xb);
    gemm_out<<<dim3(16, 32), 512, 0, stream>>>(xb, Wob, bo, (float*)d_out);
}

// Round 13
// 120.525 us; speedup vs baseline: 1.2562x; 1.2562x over previous
//
#include <hip/hip_runtime.h>
#include <hip/hip_bf16.h>

#define D_MODEL 1024
#define NHEAD 16
#define DH 64
#define BSZ 2
#define SEQ 2048
#define MROWS (BSZ*SEQ)
#define SCL_Q 0.1803368801111204f   /* (1/sqrt(64)) * log2(e) */
#define CHSZ 17408                  /* bytes per partial chunk: 128*64 bf16 + 2*128 f32 */

typedef __attribute__((ext_vector_type(4))) float f32x4;
typedef __attribute__((ext_vector_type(8))) __bf16 bf16x8;
typedef __attribute__((ext_vector_type(8))) unsigned short u16x8;

__device__ __forceinline__ float b2f(unsigned short u) {
    union { unsigned int i; float f; } v; v.i = ((unsigned int)u) << 16; return v.f;
}
__device__ __forceinline__ unsigned short f2b(float f) {
    union { float f; unsigned int i; } v; v.f = f;
    unsigned int u = v.i;
    u += 0x7fffu + ((u >> 16) & 1u);
    return (unsigned short)(u >> 16);
}

#define GLDS16(gptr, lptr) \
    __builtin_amdgcn_global_load_lds((__attribute__((address_space(1))) void*)(gptr), \
                                     (__attribute__((address_space(3))) void*)(lptr), 16, 0, 0)

// ---------------- f32 -> bf16 convert: x + 4 weight matrices in one launch ----------------
__global__ __launch_bounds__(256) void cvt5(
    const float* __restrict__ sx,
    const float* __restrict__ s1, const float* __restrict__ s2,
    const float* __restrict__ s3, const float* __restrict__ s4,
    unsigned short* __restrict__ dx,
    unsigned short* __restrict__ d1, unsigned short* __restrict__ d2,
    unsigned short* __restrict__ d3, unsigned short* __restrict__ d4)
{
    const int seg = blockIdx.y;
    const float* src; unsigned short* dst; int n4;
    if (seg == 0)      { src = sx; dst = dx; n4 = MROWS*D_MODEL/4; }
    else if (seg == 1) { src = s1; dst = d1; n4 = D_MODEL*D_MODEL/4; }
    else if (seg == 2) { src = s2; dst = d2; n4 = D_MODEL*D_MODEL/4; }
    else if (seg == 3) { src = s3; dst = d3; n4 = D_MODEL*D_MODEL/4; }
    else               { src = s4; dst = d4; n4 = D_MODEL*D_MODEL/4; }
    int i = blockIdx.x * 256 + threadIdx.x;
    int stride = gridDim.x * 256;
    for (; i < n4; i += stride) {
        float4 v = ((const float4*)src)[i];
        ushort4 o;
        o.x = f2b(v.x); o.y = f2b(v.y); o.z = f2b(v.z); o.w = f2b(v.w);
        ((ushort4*)dst)[i] = o;
    }
}

// ---------------- QKV GEMM: out = x @ W^T + b, head-split bf16 output, dbuf ----------------
// Q output (z==0) is pre-scaled by SCL_Q so attention needs no per-score scaling.
__global__ __launch_bounds__(256) void gemm_qkv(
    const unsigned short* __restrict__ X,
    const unsigned short* __restrict__ Wq, const unsigned short* __restrict__ Wk,
    const unsigned short* __restrict__ Wv,
    const float* __restrict__ bq, const float* __restrict__ bk, const float* __restrict__ bv,
    unsigned short* __restrict__ Qo, unsigned short* __restrict__ Ko, unsigned short* __restrict__ Vo)
{
    __shared__ unsigned short lsA[2][128*32];
    __shared__ unsigned short lsB[2][128*32];
    const int tid = threadIdx.x;
    const int z = blockIdx.z;
    const unsigned short* W = (z==0) ? Wq : (z==1) ? Wk : Wv;
    const float* bias = (z==0) ? bq : (z==1) ? bk : bv;
    unsigned short* Out = (z==0) ? Qo : (z==1) ? Ko : Vo;
    const int tM = blockIdx.y * 128;
    const int tN = blockIdx.x * 128;
    const int w = tid >> 6, lane = tid & 63;
    const int wr = w >> 1, wc = w & 1;
    const int lr = lane & 15, lk = lane >> 4;
    const f32x4 fz = {0.f, 0.f, 0.f, 0.f};
    f32x4 acc[4][4];
    #pragma unroll
    for (int m = 0; m < 4; m++)
        #pragma unroll
        for (int n = 0; n < 4; n++) acc[m][n] = fz;

    const int e0 = tid, e1 = 256 + tid;
    const int r0 = e0 >> 2, c0 = ((e0 & 3) ^ (r0 & 3)) * 8;
    const int r1 = e1 >> 2, c1 = ((e1 & 3) ^ (r1 & 3)) * 8;

#define GEMM_STAGE(buf, k0_) do { \
        GLDS16(X + (size_t)(tM + r0) * D_MODEL + (k0_) + c0, &lsA[buf][e0 * 8]); \
        GLDS16(X + (size_t)(tM + r1) * D_MODEL + (k0_) + c1, &lsA[buf][e1 * 8]); \
        GLDS16(W + (size_t)(tN + r0) * D_MODEL + (k0_) + c0, &lsB[buf][e0 * 8]); \
        GLDS16(W + (size_t)(tN + r1) * D_MODEL + (k0_) + c1, &lsB[buf][e1 * 8]); \
    } while (0)

    GEMM_STAGE(0, 0);
    __syncthreads();
    int cur = 0;
    for (int k0 = 0; k0 < D_MODEL; k0 += 32) {
        if (k0 + 32 < D_MODEL) GEMM_STAGE(cur ^ 1, k0 + 32);
        bf16x8 af[4], bfr[4];
        #pragma unroll
        for (int m = 0; m < 4; m++) {
            int row = wr*64 + m*16 + lr;
            af[m] = *(const bf16x8*)&lsA[cur][row*32 + ((lk ^ (row & 3)) * 8)];
        }
        #pragma unroll
        for (int n = 0; n < 4; n++) {
            int row = wc*64 + n*16 + lr;
            bfr[n] = *(const bf16x8*)&lsB[cur][row*32 + ((lk ^ (row & 3)) * 8)];
        }
        #pragma unroll
        for (int m = 0; m < 4; m++)
            #pragma unroll
            for (int n = 0; n < 4; n++)
                acc[m][n] = __builtin_amdgcn_mfma_f32_16x16x32_bf16(af[m], bfr[n], acc[m][n], 0, 0, 0);
        __syncthreads();
        cur ^= 1;
    }
#undef GEMM_STAGE
    const float qscl = (z == 0) ? SCL_Q : 1.0f;
    #pragma unroll
    for (int m = 0; m < 4; m++) {
        int ibase = tM + wr*64 + m*16 + lk*4;
        #pragma unroll
        for (int n = 0; n < 4; n++) {
            int j = tN + wc*64 + n*16 + lr;
            float bj = bias[j];
            int h = j >> 6, d = j & 63;
            #pragma unroll
            for (int r = 0; r < 4; r++) {
                int row = ibase + r;
                int b = row >> 11, s = row & 2047;
                Out[((size_t)(b*NHEAD + h) * SEQ + s) * DH + d] = f2b((acc[m][n][r] + bj) * qscl);
            }
        }
    }
}

// ---------------- Output GEMM: out = A @ W^T + b, f32 output, 128x64 tile, 8 waves ----------------
__global__ __launch_bounds__(512) void gemm_out(
    const unsigned short* __restrict__ X, const unsigned short* __restrict__ W,
    const float* __restrict__ bias, float* __restrict__ Out)
{
    __shared__ unsigned short lsA[2][128*32];
    __shared__ unsigned short lsB[2][64*32];
    const int tid = threadIdx.x;
    const int tM = blockIdx.y * 128;
    const int tN = blockIdx.x * 64;
    const int w = tid >> 6, lane = tid & 63;
    const int wr = w >> 1, wc = w & 1;
    const int lr = lane & 15, lk = lane >> 4;
    const f32x4 fz = {0.f, 0.f, 0.f, 0.f};
    f32x4 acc[2][2];
    #pragma unroll
    for (int m = 0; m < 2; m++)
        #pragma unroll
        for (int n = 0; n < 2; n++) acc[m][n] = fz;

    const int ra = tid >> 2, ca = ((tid & 3) ^ (ra & 3)) * 8;
    const int eb = tid & 255;
    const int rb = eb >> 2, cb = ((eb & 3) ^ (rb & 3)) * 8;

#define OUT_STAGE(buf, k0_) do { \
        GLDS16(X + (size_t)(tM + ra) * D_MODEL + (k0_) + ca, &lsA[buf][tid * 8]); \
        if (tid < 256) GLDS16(W + (size_t)(tN + rb) * D_MODEL + (k0_) + cb, &lsB[buf][eb * 8]); \
    } while (0)

    OUT_STAGE(0, 0);
    __syncthreads();
    int cur = 0;
    for (int k0 = 0; k0 < D_MODEL; k0 += 32) {
        if (k0 + 32 < D_MODEL) OUT_STAGE(cur ^ 1, k0 + 32);
        bf16x8 af[2], bfr[2];
        #pragma unroll
        for (int m = 0; m < 2; m++) {
            int row = wr*32 + m*16 + lr;
            af[m] = *(const bf16x8*)&lsA[cur][row*32 + ((lk ^ (row & 3)) * 8)];
        }
        #pragma unroll
        for (int n = 0; n < 2; n++) {
            int row = wc*32 + n*16 + lr;
            bfr[n] = *(const bf16x8*)&lsB[cur][row*32 + ((lk ^ (row & 3)) * 8)];
        }
        #pragma unroll
        for (int m = 0; m < 2; m++)
            #pragma unroll
            for (int n = 0; n < 2; n++)
                acc[m][n] = __builtin_amdgcn_mfma_f32_16x16x32_bf16(af[m], bfr[n], acc[m][n], 0, 0, 0);
        __syncthreads();
        cur ^= 1;
    }
#undef OUT_STAGE
    #pragma unroll
    for (int m = 0; m < 2; m++) {
        int ibase = tM + wr*32 + m*16 + lk*4;
        #pragma unroll
        for (int n = 0; n < 2; n++) {
            int j = tN + wc*32 + n*16 + lr;
            float bj = bias[j];
            #pragma unroll
            for (int r = 0; r < 4; r++)
                Out[(size_t)(ibase + r) * D_MODEL + j] = acc[m][n][r] + bj;
        }
    }
}

// ---------------- V transpose: [bh][s][d] -> [bh][d][s] ----------------
__global__ __launch_bounds__(256) void vtrans(const unsigned short* __restrict__ V,
                                              unsigned short* __restrict__ Vt) {
    __shared__ unsigned short t[64][80];
    const int bh = blockIdx.y;
    const int s0 = blockIdx.x * 64;
    const int tid = threadIdx.x;
    #pragma unroll
    for (int i = 0; i < 2; i++) {
        int e = i*256 + tid;
        int r = e >> 3, c = e & 7;
        u16x8 v = *(const u16x8*)&V[((size_t)bh * SEQ + s0 + r) * DH + c*8];
        *(u16x8*)&t[r][c*8] = v;
    }
    __syncthreads();
    #pragma unroll
    for (int i = 0; i < 2; i++) {
        int e = i*256 + tid;
        int d = e >> 3, c = e & 7;
        u16x8 o;
        #pragma unroll
        for (int j = 0; j < 8; j++) o[j] = t[c*8 + j][d];
        *(u16x8*)&Vt[((size_t)bh * DH + d) * SEQ + s0 + c*8] = o;
    }
}

// ---------------- qer[b,h,l] = dot(Qscaled[b,h,l,:], Er[l,:])  (inherits SCL_Q) ----------
// Only l >= 1024 is ever consumed (odd-k relative bias) -> compute only that half.
__global__ __launch_bounds__(256) void qer_k(const unsigned short* __restrict__ Q,
                                             const float* __restrict__ Er,
                                             float* __restrict__ qer) {
    int gw = blockIdx.x * 4 + (threadIdx.x >> 6);   // 0 .. 32*1024-1
    int lane = threadIdx.x & 63;
    int bh = gw >> 10;
    int l = 1024 + (gw & 1023);
    float p = b2f(Q[((size_t)bh * SEQ + l) * DH + lane]) * Er[l * DH + lane];
    #pragma unroll
    for (int m = 32; m >= 1; m >>= 1) p += __shfl_xor(p, m, 64);
    if (lane == 0) qer[(size_t)bh * SEQ + l] = p;
}

// ---------------- flash attention, swapped-QK, QBLK=128, 4 waves x 32q, chunked ----------------
// Fixed-shift softmax (no online max). Per-iter bias (qer) register loads issued before
// the global_load_lds prefetch (in-order vmcnt queue: keeps prefetch in flight).
// Empirically best configuration (r8/r9): 4 waves x 32q, 48KB LDS, coarse split-k.
__global__ __launch_bounds__(256, 3) void attn_k(
    const unsigned short* __restrict__ Q, const unsigned short* __restrict__ Kg,
    const unsigned short* __restrict__ Vt, const float* __restrict__ qer,
    unsigned short* __restrict__ Om, char* __restrict__ part)
{
    __shared__ unsigned short lsK[2][64*64];   // 16 KB
    __shared__ unsigned short lsV[2][64*64];   // 16 KB
    __shared__ unsigned short lsP[128*64];     // 16 KB
    // entry table, work-descending: v = (j<<2) | (split<<1) | half
    const unsigned char tab[24] = {
        (7<<2),        (15<<2)|2, (15<<2)|3, (14<<2)|2, (14<<2)|3,
        (6<<2),        (13<<2)|2, (13<<2)|3, (12<<2)|2, (12<<2)|3,
        (5<<2),        (11<<2)|2, (11<<2)|3, (10<<2)|2, (10<<2)|3,
        (4<<2),        (9<<2)|2,  (9<<2)|3,  (8<<2)|2,  (8<<2)|3,
        (3<<2), (2<<2), (1<<2), (0<<2)
    };
    const int id = blockIdx.x;
    const int bh = id & 31;
    const int v = tab[id >> 5];
    const int j = v >> 2;
    const bool split = (v >> 1) & 1;
    const int half = v & 1;
    const int kt0 = (split && half) ? (j + 1) : 0;
    const int ktN = (split && !half) ? (j + 1) : (2*j + 2);
    const int b = bh >> 4, h = bh & 15;
    const int tid = threadIdx.x;
    const int w = tid >> 6, lane = tid & 63;
    const int lr = lane & 15, lk = lane >> 4;
    const int q0 = w*32 + lr, q1 = q0 + 16;     // 0..127
    const int qrow0 = j*128 + q0, qrow1 = qrow0 + 16;
    const f32x4 fz = {0.f, 0.f, 0.f, 0.f};

    const unsigned short* Qr0 = Q + ((size_t)bh * SEQ + qrow0) * DH;
    const unsigned short* Qr1 = Q + ((size_t)bh * SEQ + qrow1) * DH;
    bf16x8 bqa0 = *(const bf16x8*)&Qr0[lk*8];
    bf16x8 bqa1 = *(const bf16x8*)&Qr0[32 + lk*8];
    bf16x8 bqb0 = *(const bf16x8*)&Qr1[lk*8];
    bf16x8 bqb1 = *(const bf16x8*)&Qr1[32 + lk*8];

    // staging: 2x 16B loads per thread per matrix per 64x64 tile (pre-swizzled source)
    const int sr0 = tid >> 3,          sc0 = ((tid & 7) ^ (sr0 & 7)) * 8;
    const int sr1 = (256 + tid) >> 3,  sc1 = (((256 + tid) & 7) ^ (sr1 & 7)) * 8;
    const unsigned short* kst0 = Kg + ((size_t)bh * SEQ + kt0*64 + sr0) * DH + sc0;
    const unsigned short* kst1 = Kg + ((size_t)bh * SEQ + kt0*64 + sr1) * DH + sc1;
    const unsigned short* vst0 = Vt + ((size_t)bh * DH + sr0) * SEQ + kt0*64 + sc0;
    const unsigned short* vst1 = Vt + ((size_t)bh * DH + sr1) * SEQ + kt0*64 + sc1;
    const float* qb = qer + (size_t)bh * SEQ + 1024 + kt0*32 + lk*2;

#define ATTN_STAGE(buf) do { \
        GLDS16(kst0, &lsK[buf][tid * 8]);        kst0 += 64*DH; \
        GLDS16(kst1, &lsK[buf][(256+tid) * 8]);  kst1 += 64*DH; \
        GLDS16(vst0, &lsV[buf][tid * 8]);        vst0 += 64; \
        GLDS16(vst1, &lsV[buf][(256+tid) * 8]);  vst1 += 64; \
    } while (0)

    f32x4 o0[4], o1[4];
    #pragma unroll
    for (int df = 0; df < 4; df++) { o0[df] = fz; o1[df] = fz; }
    float lp0 = 0.0f, lp1 = 0.0f;   // per-lane row-sum partials (this lane's k slots)

    ATTN_STAGE(0);
    __syncthreads();
    int cur = 0;

    for (int kt = kt0; kt < ktN; kt++) {
        // bias loads first (older than the stage ops on the in-order vmcnt queue)
        float2 bv[4];
        #pragma unroll
        for (int kf = 0; kf < 4; kf++) bv[kf] = *(const float2*)(qb + kf*8);
        qb += 32;
        if (kt + 1 < ktN) ATTN_STAGE(cur ^ 1);   // prefetch; drains at end-of-iter barrier
        // QK^T (swapped): st/su[kf][r] = S[k = kt*64+kf*16+lk*4+r][qrow0/qrow1], log2 domain
        float st[4][4], su[4][4];
        __builtin_amdgcn_s_setprio(1);
        #pragma unroll
        for (int kf = 0; kf < 4; kf++) {
            int row = kf*16 + lr;
            bf16x8 a0 = *(const bf16x8*)&lsK[cur][row*64 + ((lk ^ (row & 7)) * 8)];
            bf16x8 a1 = *(const bf16x8*)&lsK[cur][row*64 + (((4 + lk) ^ (row & 7)) * 8)];
            f32x4 zv = fz, yv = fz;
            zv = __builtin_amdgcn_mfma_f32_16x16x32_bf16(a0, bqa0, zv, 0, 0, 0);
            zv = __builtin_amdgcn_mfma_f32_16x16x32_bf16(a1, bqa1, zv, 0, 0, 0);
            yv = __builtin_amdgcn_mfma_f32_16x16x32_bf16(a0, bqb0, yv, 0, 0, 0);
            yv = __builtin_amdgcn_mfma_f32_16x16x32_bf16(a1, bqb1, yv, 0, 0, 0);
            st[kf][0] = zv[0];
            st[kf][1] = zv[1] + bv[kf].x;
            st[kf][2] = zv[2];
            st[kf][3] = zv[3] + bv[kf].y;
            su[kf][0] = yv[0];
            su[kf][1] = yv[1] + bv[kf].x;
            su[kf][2] = yv[2];
            su[kf][3] = yv[3] + bv[kf].y;
        }
        __builtin_amdgcn_s_setprio(0);
        if (kt >= 2*j) {  // tiles that can cross the diagonal
            #pragma unroll
            for (int kf = 0; kf < 4; kf++) {
                int kg0 = kt*64 + kf*16 + lk*4;
                #pragma unroll
                for (int r = 0; r < 4; r++) {
                    if (kg0 + r > qrow0) st[kf][r] = -3.0e38f;
                    if (kg0 + r > qrow1) su[kf][r] = -3.0e38f;
                }
            }
        }
        // p = exp2(S) (fixed shift), per-lane partial row-sums, pack to LDS
        #pragma unroll
        for (int kf = 0; kf < 4; kf++) {
            float p0 = exp2f(st[kf][0]);
            float p1 = exp2f(st[kf][1]);
            float p2 = exp2f(st[kf][2]);
            float p3 = exp2f(st[kf][3]);
            lp0 += (p0 + p1) + (p2 + p3);
            union { __hip_bfloat162 h2[2]; unsigned long long u; } pk;
            pk.h2[0] = __float22bfloat162_rn(float2{p0, p1});
            pk.h2[1] = __float22bfloat162_rn(float2{p2, p3});
            *(unsigned long long*)&lsP[q0*64 + ((((kf<<2)|lk) ^ ((lr&7)<<1))<<2)] = pk.u;
            float s0 = exp2f(su[kf][0]);
            float s1 = exp2f(su[kf][1]);
            float s2 = exp2f(su[kf][2]);
            float s3 = exp2f(su[kf][3]);
            lp1 += (s0 + s1) + (s2 + s3);
            pk.h2[0] = __float22bfloat162_rn(float2{s0, s1});
            pk.h2[1] = __float22bfloat162_rn(float2{s2, s3});
            *(unsigned long long*)&lsP[q1*64 + ((((kf<<2)|lk) ^ ((lr&7)<<1))<<2)] = pk.u;
        }
        // P^T reads (own rows only -> same-wave lgkm dependency)
        bf16x8 pa0 = *(const bf16x8*)&lsP[q0*64 + ((lk ^ (lr&7))<<3)];
        bf16x8 pa1 = *(const bf16x8*)&lsP[q0*64 + (((4+lk) ^ (lr&7))<<3)];
        bf16x8 pb0 = *(const bf16x8*)&lsP[q1*64 + ((lk ^ (lr&7))<<3)];
        bf16x8 pb1 = *(const bf16x8*)&lsP[q1*64 + (((4+lk) ^ (lr&7))<<3)];
        // PV (swapped): shared V fragments feed both q-halves
        __builtin_amdgcn_s_setprio(1);
        #pragma unroll
        for (int df = 0; df < 4; df++) {
            int row = df*16 + lr;
            bf16x8 v0 = *(const bf16x8*)&lsV[cur][row*64 + ((lk ^ (row & 7)) * 8)];
            bf16x8 v1 = *(const bf16x8*)&lsV[cur][row*64 + (((4 + lk) ^ (row & 7)) * 8)];
            o0[df] = __builtin_amdgcn_mfma_f32_16x16x32_bf16(v0, pa0, o0[df], 0, 0, 0);
            o0[df] = __builtin_amdgcn_mfma_f32_16x16x32_bf16(v1, pa1, o0[df], 0, 0, 0);
            o1[df] = __builtin_amdgcn_mfma_f32_16x16x32_bf16(v0, pb0, o1[df], 0, 0, 0);
            o1[df] = __builtin_amdgcn_mfma_f32_16x16x32_bf16(v1, pb1, o1[df], 0, 0, 0);
        }
        __builtin_amdgcn_s_setprio(0);
        __syncthreads();
        cur ^= 1;
    }
#undef ATTN_STAGE
    // final row-sum reduction across the 4 lk groups (2 shuffles, once per chunk)
    float l0 = lp0 + __shfl_xor(lp0, 16, 64);
    l0 += __shfl_xor(l0, 32, 64);
    float l1 = lp1 + __shfl_xor(lp1, 16, 64);
    l1 += __shfl_xor(l1, 32, 64);
    if (split) {
        char* cb = part + (size_t)((bh*8 + (j - 8))*2 + half) * CHSZ;
        unsigned short* ob = (unsigned short*)cb;
        #pragma unroll
        for (int df = 0; df < 4; df++) {
            ushort4 ov;
            ov.x = f2b(o0[df][0]); ov.y = f2b(o0[df][1]);
            ov.z = f2b(o0[df][2]); ov.w = f2b(o0[df][3]);
            *(ushort4*)&ob[q0*64 + df*16 + lk*4] = ov;
            ov.x = f2b(o1[df][0]); ov.y = f2b(o1[df][1]);
            ov.z = f2b(o1[df][2]); ov.w = f2b(o1[df][3]);
            *(ushort4*)&ob[q1*64 + df*16 + lk*4] = ov;
        }
        float* ml = (float*)(cb + 16384);
        if (lk == 0) {
            ml[q0] = 0.0f; ml[128 + q0] = l0;
            ml[q1] = 0.0f; ml[128 + q1] = l1;
        }
    } else {
        float inv0 = 1.0f / l0, inv1 = 1.0f / l1;
        #pragma unroll
        for (int df = 0; df < 4; df++) {
            ushort4 ov;
            ov.x = f2b(o0[df][0] * inv0);
            ov.y = f2b(o0[df][1] * inv0);
            ov.z = f2b(o0[df][2] * inv0);
            ov.w = f2b(o0[df][3] * inv0);
            *(ushort4*)&Om[((size_t)(b * SEQ + qrow0)) * D_MODEL + h*64 + df*16 + lk*4] = ov;
            ov.x = f2b(o1[df][0] * inv1);
            ov.y = f2b(o1[df][1] * inv1);
            ov.z = f2b(o1[df][2] * inv1);
            ov.w = f2b(o1[df][3] * inv1);
            *(ushort4*)&Om[((size_t)(b * SEQ + qrow1)) * D_MODEL + h*64 + df*16 + lk*4] = ov;
        }
    }
}

// ---------------- merge the two split-k partials for j >= 8 ----------------
__global__ __launch_bounds__(256) void attn_merge(const char* __restrict__ part,
                                                  unsigned short* __restrict__ Om)
{
    const int bh = blockIdx.x & 31, jj = blockIdx.x >> 5;
    const int b = bh >> 4, h = bh & 15, j = 8 + jj;
    const char* c0 = part + (size_t)((bh*8 + jj)*2) * CHSZ;
    const char* c1 = c0 + CHSZ;
    const unsigned short* o0 = (const unsigned short*)c0;
    const unsigned short* o1 = (const unsigned short*)c1;
    const float* ml0 = (const float*)(c0 + 16384);
    const float* ml1 = (const float*)(c1 + 16384);
    const int t = threadIdx.x;
    const int q = t >> 1, dh = (t & 1) * 32;
    float m0 = ml0[q], l0 = ml0[128 + q];
    float m1 = ml1[q], l1 = ml1[128 + q];
    float M = fmaxf(m0, m1);
    float w0 = exp2f(m0 - M), w1 = exp2f(m1 - M);
    float inv = 1.0f / (l0 * w0 + l1 * w1);
    w0 *= inv; w1 *= inv;
    unsigned short* dst = Om + ((size_t)(b*SEQ + j*128 + q)) * D_MODEL + h*64 + dh;
    #pragma unroll
    for (int i = 0; i < 4; i++) {
        u16x8 a = *(const u16x8*)&o0[q*64 + dh + i*8];
        u16x8 c = *(const u16x8*)&o1[q*64 + dh + i*8];
        u16x8 ov;
        #pragma unroll
        for (int r = 0; r < 8; r++)
            ov[r] = f2b(b2f(a[r])*w0 + b2f(c[r])*w1);
        *(u16x8*)&dst[i*8] = ov;
    }
}

extern "C" void kernel_launch(void* const* d_in, const int* in_sizes, int n_in,
                              void* d_out, int out_size, void* d_ws, size_t ws_size,
                              hipStream_t stream) {
    const float* x  = (const float*)d_in[0];
    const float* Wq = (const float*)d_in[1];
    const float* bq = (const float*)d_in[2];
    const float* Wk = (const float*)d_in[3];
    const float* bk = (const float*)d_in[4];
    const float* Wv = (const float*)d_in[5];
    const float* bv = (const float*)d_in[6];
    const float* Wo = (const float*)d_in[7];
    const float* bo = (const float*)d_in[8];
    const float* Er = (const float*)d_in[9];

    char* ws = (char*)d_ws;
    const size_t MB = 1024*1024;
    unsigned short* xb  = (unsigned short*)(ws);              // 8 MB: x bf16; reused as attn out
    unsigned short* Wqb = (unsigned short*)(ws + 8*MB);       // 2 MB each
    unsigned short* Wkb = (unsigned short*)(ws + 10*MB);
    unsigned short* Wvb = (unsigned short*)(ws + 12*MB);
    unsigned short* Wob = (unsigned short*)(ws + 14*MB);
    unsigned short* Qb  = (unsigned short*)(ws + 16*MB);      // 8 MB
    unsigned short* Kb  = (unsigned short*)(ws + 24*MB);      // 8 MB
    unsigned short* Vb  = (unsigned short*)(ws + 32*MB);      // 8 MB ([bh][s][d])
    unsigned short* Vtb = (unsigned short*)(ws + 40*MB);      // 8 MB ([bh][d][s])
    float* qer          = (float*)(ws + 48*MB);               // 256 KB
    char*  part         = (char*)(ws + 48*MB + 262144);       // 8.9 MB partials

    cvt5<<<dim3(1024, 5), 256, 0, stream>>>(x, Wq, Wk, Wv, Wo, xb, Wqb, Wkb, Wvb, Wob);

    gemm_qkv<<<dim3(8, 32, 3), 256, 0, stream>>>(xb, Wqb, Wkb, Wvb, bq, bk, bv, Qb, Kb, Vb);
    vtrans<<<dim3(32, 32), 256, 0, stream>>>(Vb, Vtb);
    qer_k<<<8192, 256, 0, stream>>>(Qb, Er, qer);
    attn_k<<<768, 256, 0, stream>>>(Qb, Kb, Vtb, qer, xb, part);
    attn_merge<<<256, 256, 0, stream>>>(part, xb);
    gemm_out<<<dim3(16, 32), 512, 0, stream>>>(xb, Wob, bo, (float*)d_out);
}